// Round 1
// 1939.204 us; speedup vs baseline: 1.3616x; 1.3616x over previous
//
#include <hip/hip_runtime.h>
#include <hip/hip_fp16.h>
#include <math.h>

// Problem constants (match reference)
constexpr int kP  = 3;
constexpr int kN  = 50000;
constexpr int kE  = 256000;
constexpr int kC  = 5;
constexpr int kF  = 68;    // F_IN + F_NODE
constexpr int kF2 = 136;   // 2*F
constexpr int kFE = 16;    // F_EDGE
constexpr int kFN = 64;    // F_NODE
constexpr int kOfsStride = 50004;  // (N+1) rounded up to mult of 4 ints

__device__ __forceinline__ float fast_tanh(float x) {
  float t = fminf(fmaxf(x, -15.f), 15.f);
  float e = __expf(2.f * t);
  return (e - 1.f) / (e + 1.f);
}

// ---------------------------------------------------------------------------
// 1) Histogram of in-degrees (all planes): counts[p][dst]++
// ---------------------------------------------------------------------------
__global__ __launch_bounds__(256) void hist_kernel(
    const int* __restrict__ ei,   // [P, 2, E]
    int* __restrict__ counts)     // [P, N]
{
  int p = blockIdx.y;
  int e = blockIdx.x * 256 + threadIdx.x;
  if (e >= kE) return;
  int dst = ei[(size_t)p * 2 * kE + kE + e];
  atomicAdd(&counts[p * kN + dst], 1);
}

// ---------------------------------------------------------------------------
// 2) Exclusive scan per plane (one 1024-thread block per plane).
// ---------------------------------------------------------------------------
__global__ __launch_bounds__(1024) void scan_kernel(
    const int* __restrict__ counts,  // [P, N]
    int* __restrict__ offsets,       // [P, kOfsStride]
    int* __restrict__ cursor)        // [P, N]
{
  int p = blockIdx.x;
  const int* cnt = counts + p * kN;
  int* ofs = offsets + p * kOfsStride;
  int* cur = cursor + p * kN;
  __shared__ int buf[1024];
  __shared__ int carry_s;
  int tid = threadIdx.x;
  if (tid == 0) carry_s = 0;
  __syncthreads();
  for (int base = 0; base < kN; base += 1024) {
    int i = base + tid;
    int v = (i < kN) ? cnt[i] : 0;
    buf[tid] = v;
    __syncthreads();
    for (int d = 1; d < 1024; d <<= 1) {
      int t = (tid >= d) ? buf[tid - d] : 0;
      __syncthreads();
      buf[tid] += t;
      __syncthreads();
    }
    int incl = buf[tid];
    int carry = carry_s;
    if (i < kN) {
      int excl = carry + incl - v;
      ofs[i] = excl;
      cur[i] = excl;
    }
    __syncthreads();
    if (tid == 1023) carry_s = carry + incl;
    __syncthreads();
  }
  if (tid == 0) ofs[kN] = carry_s;
}

// ---------------------------------------------------------------------------
// 3) Per-node edge-layer-1 precompute:
//    yi[n,c,g] = We1[c][g][0:68]   . x[n,c,:]
//    yj[n,c,g] = We1[c][g][68:136] . x[n,c,:]
// ---------------------------------------------------------------------------
__global__ __launch_bounds__(256) void pre_kernel(
    const float* __restrict__ x,    // [N, C, F] (this plane)
    const float* __restrict__ We1,  // [C, 16, 136]
    float* __restrict__ yi,         // [N, C, 16]
    float* __restrict__ yj)         // [N, C, 16]
{
  int n = blockIdx.x * 256 + threadIdx.x;
  int c = blockIdx.y;
  if (n >= kN) return;

  const float4* xr = reinterpret_cast<const float4*>(x + ((size_t)n * kC + c) * kF);
  const float* Wc = We1 + c * (kFE * kF2);

  float ai[kFE], aj[kFE];
#pragma unroll
  for (int g = 0; g < kFE; ++g) { ai[g] = 0.f; aj[g] = 0.f; }

  for (int q = 0; q < kF / 4; ++q) {  // 17
    float4 v = xr[q];
#pragma unroll
    for (int g = 0; g < kFE; ++g) {
      const float* wi = Wc + g * kF2 + 4 * q;
      const float* wj = wi + kF;
      float a = ai[g];
      a = fmaf(wi[0], v.x, a); a = fmaf(wi[1], v.y, a);
      a = fmaf(wi[2], v.z, a); a = fmaf(wi[3], v.w, a);
      ai[g] = a;
      float b = aj[g];
      b = fmaf(wj[0], v.x, b); b = fmaf(wj[1], v.y, b);
      b = fmaf(wj[2], v.z, b); b = fmaf(wj[3], v.w, b);
      aj[g] = b;
    }
  }

  float4* oi = reinterpret_cast<float4*>(yi + ((size_t)n * kC + c) * kFE);
  float4* oj = reinterpret_cast<float4*>(yj + ((size_t)n * kC + c) * kFE);
#pragma unroll
  for (int k = 0; k < 4; ++k) {
    oi[k] = make_float4(ai[4*k], ai[4*k+1], ai[4*k+2], ai[4*k+3]);
    oj[k] = make_float4(aj[4*k], aj[4*k+1], aj[4*k+2], aj[4*k+3]);
  }
}

// ---------------------------------------------------------------------------
// 3b) Per-node aggr-half precompute of node layer 1:
//     z[n,c,g] = Wn1[c][g][68:136] . x[n,c,:]    (stored fp16)
//     This hoists the per-edge matmul out of the gather: the node kernel
//     then accumulates h[g] += w_s * z[src][g] over contiguous 128-B rows.
// ---------------------------------------------------------------------------
__global__ __launch_bounds__(256) void pre_z_kernel(
    const float* __restrict__ x,    // [N, C, F] (this plane)
    const float* __restrict__ Wn1,  // [C, 64, 136]
    __half* __restrict__ z)         // [N, C, 64]
{
  int n = blockIdx.x * 256 + threadIdx.x;
  int c = blockIdx.y;
  if (n >= kN) return;

  // x row resident in registers (17 float4 = 68 VGPRs)
  float4 xr[kF / 4];
  const float4* xp = reinterpret_cast<const float4*>(x + ((size_t)n * kC + c) * kF);
#pragma unroll
  for (int q = 0; q < kF / 4; ++q) xr[q] = xp[q];

  const float* W = Wn1 + c * (kFN * kF2) + kF;  // aggr-half columns
  uint4* zp = reinterpret_cast<uint4*>(z + ((size_t)n * kC + c) * kFN);

  for (int g0 = 0; g0 < kFN; g0 += 8) {
    float acc[8];
#pragma unroll
    for (int t = 0; t < 8; ++t) acc[t] = 0.f;
#pragma unroll
    for (int q = 0; q < kF / 4; ++q) {
      float4 v = xr[q];
#pragma unroll
      for (int t = 0; t < 8; ++t) {
        const float* wr = W + (size_t)(g0 + t) * kF2 + 4 * q;  // uniform -> s_load
        float a = acc[t];
        a = fmaf(wr[0], v.x, a); a = fmaf(wr[1], v.y, a);
        a = fmaf(wr[2], v.z, a); a = fmaf(wr[3], v.w, a);
        acc[t] = a;
      }
    }
    __half2 p0 = __floats2half2_rn(acc[0], acc[1]);
    __half2 p1 = __floats2half2_rn(acc[2], acc[3]);
    __half2 p2 = __floats2half2_rn(acc[4], acc[5]);
    __half2 p3 = __floats2half2_rn(acc[6], acc[7]);
    uint4 pk;
    pk.x = *reinterpret_cast<unsigned int*>(&p0);
    pk.y = *reinterpret_cast<unsigned int*>(&p1);
    pk.z = *reinterpret_cast<unsigned int*>(&p2);
    pk.w = *reinterpret_cast<unsigned int*>(&p3);
    zp[g0 >> 3] = pk;
  }
}

// ---------------------------------------------------------------------------
// 4) Edge kernel: softmax weights from precomputed yi/yj, scattered into the
//    CSR slot claimed via cursor (int atomic). No float atomics anywhere.
// ---------------------------------------------------------------------------
__global__ __launch_bounds__(256) void edge_kernel(
    const int*   __restrict__ ei,         // [2, E] (this plane)
    const float* __restrict__ yi,         // [N, C, 16]
    const float* __restrict__ yj,         // [N, C, 16]
    const float* __restrict__ be1,        // [C, 16]
    const float* __restrict__ We2,        // [C, 16]
    const float* __restrict__ be2,        // [C]
    int*         __restrict__ cursor,     // [N] (this plane)
    int*         __restrict__ sorted_src, // [E]
    float*       __restrict__ w_sorted)   // [E, C]
{
  int e = blockIdx.x * 256 + threadIdx.x;
  if (e >= kE) return;
  int src = ei[e];
  int dst = ei[kE + e];

  const float* yid = yi + (size_t)dst * (kC * kFE);
  const float* yjs = yj + (size_t)src * (kC * kFE);

  float logits[kC];
#pragma unroll
  for (int c = 0; c < kC; ++c) {
    const float4* a = reinterpret_cast<const float4*>(yid + c * kFE);
    const float4* b = reinterpret_cast<const float4*>(yjs + c * kFE);
    float lg = be2[c];
#pragma unroll
    for (int qq = 0; qq < 4; ++qq) {
      float4 av = a[qq];
      float4 bv = b[qq];
      const float* bb = be1 + c * kFE + 4 * qq;
      const float* w2 = We2 + c * kFE + 4 * qq;
      lg = fmaf(w2[0], fast_tanh(av.x + bv.x + bb[0]), lg);
      lg = fmaf(w2[1], fast_tanh(av.y + bv.y + bb[1]), lg);
      lg = fmaf(w2[2], fast_tanh(av.z + bv.z + bb[2]), lg);
      lg = fmaf(w2[3], fast_tanh(av.w + bv.w + bb[3]), lg);
    }
    logits[c] = lg;
  }

  float m = logits[0];
#pragma unroll
  for (int c = 1; c < kC; ++c) m = fmaxf(m, logits[c]);
  float wgt[kC];
  float s = 0.f;
#pragma unroll
  for (int c = 0; c < kC; ++c) { wgt[c] = __expf(logits[c] - m); s += wgt[c]; }
  float inv = 1.f / s;

  int pos = atomicAdd(&cursor[dst], 1);
  sorted_src[pos] = src;
#pragma unroll
  for (int c = 0; c < kC; ++c) w_sorted[(size_t)pos * kC + c] = wgt[c] * inv;
}

// ---------------------------------------------------------------------------
// 5) Node kernel: gather accumulates h[64] directly from contiguous z rows
//    (edge arrays read ONCE, 128-B fully-used lines), then x-half of layer 1,
//    tanh, layer 2. h never leaves registers.
// ---------------------------------------------------------------------------
__global__ __launch_bounds__(256) void node_kernel(
    const float*  __restrict__ x,          // [N, C, F] (this plane)
    const int*    __restrict__ offsets,    // [N+1] (this plane)
    const int*    __restrict__ sorted_src, // [E]
    const float*  __restrict__ w_sorted,   // [E, C]
    const __half* __restrict__ z,          // [N, C, 64]
    const float*  __restrict__ Wn1,        // [C, 64, 136]
    const float*  __restrict__ bn1,        // [C, 64]
    const float*  __restrict__ Wn2,        // [C, 64, 64]
    const float*  __restrict__ bn2,        // [C, 64]
    float*        __restrict__ out)        // [N, C, 64] (this plane)
{
  int n = blockIdx.x * 256 + threadIdx.x;
  int c = blockIdx.y;
  if (n >= kN) return;

  int beg = offsets[n];
  int end = offsets[n + 1];

  float h[kFN];
#pragma unroll
  for (int g = 0; g < kFN; ++g) h[g] = 0.f;

  // Gather: h[g] += w_s * z[src][c][g]; one contiguous 128-B row per edge.
  for (int s = beg; s < end; ++s) {
    int sj = sorted_src[s];
    float w = w_sorted[(size_t)s * kC + c];
    const uint4* zp = reinterpret_cast<const uint4*>(z + ((size_t)sj * kC + c) * kFN);
#pragma unroll
    for (int u = 0; u < 8; ++u) {
      uint4 v = zp[u];
      float2 f0 = __half22float2(*reinterpret_cast<const __half2*>(&v.x));
      float2 f1 = __half22float2(*reinterpret_cast<const __half2*>(&v.y));
      float2 f2 = __half22float2(*reinterpret_cast<const __half2*>(&v.z));
      float2 f3 = __half22float2(*reinterpret_cast<const __half2*>(&v.w));
      h[8*u+0] = fmaf(w, f0.x, h[8*u+0]);
      h[8*u+1] = fmaf(w, f0.y, h[8*u+1]);
      h[8*u+2] = fmaf(w, f1.x, h[8*u+2]);
      h[8*u+3] = fmaf(w, f1.y, h[8*u+3]);
      h[8*u+4] = fmaf(w, f2.x, h[8*u+4]);
      h[8*u+5] = fmaf(w, f2.y, h[8*u+5]);
      h[8*u+6] = fmaf(w, f3.x, h[8*u+6]);
      h[8*u+7] = fmaf(w, f3.y, h[8*u+7]);
    }
  }

  // x-half of node layer 1 (weights uniform per block -> scalar loads)
  const float* W1 = Wn1 + c * (kFN * kF2);
  const float4* xp = reinterpret_cast<const float4*>(x + ((size_t)n * kC + c) * kF);
  for (int q = 0; q < kF / 4; ++q) {  // 17
    float4 v = xp[q];
#pragma unroll
    for (int g = 0; g < kFN; ++g) {
      const float* wr = W1 + (size_t)g * kF2 + 4 * q;
      float a = h[g];
      a = fmaf(wr[0], v.x, a);
      a = fmaf(wr[1], v.y, a);
      a = fmaf(wr[2], v.z, a);
      a = fmaf(wr[3], v.w, a);
      h[g] = a;
    }
  }

  const float* b1 = bn1 + c * kFN;
#pragma unroll
  for (int g = 0; g < kFN; ++g) h[g] = fast_tanh(h[g] + b1[g]);

  // Layer 2, 4 outputs at a time -> float4 stores
  const float* W2 = Wn2 + c * (kFN * kFN);
  const float* b2 = bn2 + c * kFN;
  float4* op = reinterpret_cast<float4*>(out + ((size_t)n * kC + c) * kFN);
  for (int g2 = 0; g2 < kFN; g2 += 4) {
    float a0 = b2[g2], a1 = b2[g2 + 1], a2 = b2[g2 + 2], a3 = b2[g2 + 3];
    const float* w0 = W2 + (size_t)g2 * kFN;
#pragma unroll
    for (int k = 0; k < kFN; ++k) {
      float hk = h[k];
      a0 = fmaf(w0[k],            hk, a0);
      a1 = fmaf(w0[kFN + k],      hk, a1);
      a2 = fmaf(w0[2 * kFN + k],  hk, a2);
      a3 = fmaf(w0[3 * kFN + k],  hk, a3);
    }
    op[g2 >> 2] = make_float4(fast_tanh(a0), fast_tanh(a1),
                              fast_tanh(a2), fast_tanh(a3));
  }
}

// ---------------------------------------------------------------------------
extern "C" void kernel_launch(void* const* d_in, const int* in_sizes, int n_in,
                              void* d_out, int out_size, void* d_ws, size_t ws_size,
                              hipStream_t stream) {
  const float* x   = (const float*)d_in[0];   // [P, N, C, F]
  const int*   ei  = (const int*)  d_in[1];   // [P, 2, E] (int32 from harness)
  const float* We1 = (const float*)d_in[2];   // [P, C, 16, 136]
  const float* be1 = (const float*)d_in[3];   // [P, C, 16]
  const float* We2 = (const float*)d_in[4];   // [P, C, 1, 16]
  const float* be2 = (const float*)d_in[5];   // [P, C, 1]
  const float* Wn1 = (const float*)d_in[6];   // [P, C, 64, 136]
  const float* bn1 = (const float*)d_in[7];   // [P, C, 64]
  const float* Wn2 = (const float*)d_in[8];   // [P, C, 64, 64]
  const float* bn2 = (const float*)d_in[9];   // [P, C, 64]
  float* out = (float*)d_out;                 // [P, N, C, 64]

  // Workspace layout (all 16B-aligned; ~40 MB total).
  // z (fp16, 32 MB) exactly overlays yi+yj (32 MB): yi/yj are dead after
  // edge_kernel, z is written after it and consumed by node_kernel, and the
  // next plane's pre_kernel rewrites yi/yj only after node_kernel finished
  // (stream-serialized).
  int* counts  = (int*)d_ws;                       // P*N ints
  int* offsets = counts + kP * kN;                 // P*kOfsStride ints
  int* cursor  = offsets + kP * kOfsStride;        // P*N ints
  int* sorted_src = cursor + kP * kN;              // E ints (per-plane reuse)
  float* w_sorted = (float*)(sorted_src + kE);     // E*C floats (reuse)
  float* yi = w_sorted + (size_t)kE * kC;          // N*C*16 floats (reuse)
  float* yj = yi + (size_t)kN * kC * kFE;          // N*C*16 floats (reuse)
  __half* z = (__half*)yi;                         // N*C*64 halves (overlay)

  const size_t planeX = (size_t)kN * kC * kF;

  hipMemsetAsync(counts, 0, (size_t)kP * kN * sizeof(int), stream);
  hist_kernel<<<dim3(kE / 256, kP), 256, 0, stream>>>(ei, counts);
  scan_kernel<<<kP, 1024, 0, stream>>>(counts, offsets, cursor);

  for (int p = 0; p < kP; ++p) {
    const float* xp = x + p * planeX;

    pre_kernel<<<dim3((kN + 255) / 256, kC), 256, 0, stream>>>(
        xp, We1 + (size_t)p * kC * kFE * kF2, yi, yj);

    edge_kernel<<<kE / 256, 256, 0, stream>>>(
        ei + (size_t)p * 2 * kE, yi, yj,
        be1 + (size_t)p * kC * kFE,
        We2 + (size_t)p * kC * kFE,
        be2 + (size_t)p * kC,
        cursor + p * kN, sorted_src, w_sorted);

    pre_z_kernel<<<dim3((kN + 255) / 256, kC), 256, 0, stream>>>(
        xp, Wn1 + (size_t)p * kC * kFN * kF2, z);

    node_kernel<<<dim3((kN + 255) / 256, kC), 256, 0, stream>>>(
        xp, offsets + p * kOfsStride, sorted_src, w_sorted, z,
        Wn1 + (size_t)p * kC * kFN * kF2,
        bn1 + (size_t)p * kC * kFN,
        Wn2 + (size_t)p * kC * kFN * kFN,
        bn2 + (size_t)p * kC * kFN,
        out + (size_t)p * kN * kC * kFN);
  }
}